// Round 11
// baseline (430.478 us; speedup 1.0000x reference)
//
#include <hip/hip_runtime.h>
#include <hip/hip_cooperative_groups.h>

namespace cg = cooperative_groups;

#define NN 100000
#define EE 1600000
#define DTc 0.1f
#define REGc 1e-6f
#define WQc (1.0f / 64.0f)

#define NB 782              // ceil(NN/128) buckets of 128 nodes
#define CAP 4608            // bucket capacity (mean 4092 + 8 sigma) — LDS-fit
#define BCHUNK 16384        // edges per bin block (big runs -> coalesced writes)
#define BS_NB 98            // ceil(EE/BCHUNK)
#define ACT_S 72            // padded LDS row stride (bf16) in node_kernel
#define PRE_NB 3125         // NN*64 floats / (256 thr * 8 floats) exact
#define WP_NB 80            // 5*4096/256 exact
#define SIDE_BIT (1u << 24) // entry is src-side (local == src of the edge)

typedef unsigned long long u64;
typedef __attribute__((ext_vector_type(8))) short short8;
typedef __attribute__((ext_vector_type(4))) float f32x4;

__device__ __forceinline__ unsigned short f2bf(float x) {
    unsigned u = __float_as_uint(x);
    unsigned r = (u + 0x7fffu + ((u >> 16) & 1u)) >> 16;   // RNE
    return (unsigned short)r;
}
__device__ __forceinline__ float bf2f(unsigned short s) {
    return __uint_as_float(((unsigned)s) << 16);
}
__device__ __forceinline__ unsigned pack2(float a, float b) {
    return (unsigned)f2bf(fmaxf(a, 0.f)) | ((unsigned)f2bf(fmaxf(b, 0.f)) << 16);
}

// ---------------------------------------------------------------------------
// Mega prep. Block ranges (bin blocks FIRST so their atomic/scatter latency
// hides under the streaming blocks co-resident behind them):
//   [0, BS_NB)          -> self-reserving binned scatter of 16384 edges
//                          (2-pass over the L2-hot window: histogram ->
//                          one reservation atomic per touched bucket ->
//                          placement; runs ~42 entries = ~full cachelines)
//   [BS_NB, +PRE_NB)    -> f+ = relu(f) as bf16, 8 floats/thread
//   [BS_NB+PRE_NB, ..)  -> transposed bf16 weights
// entry = (f32 w)<<32 | side<<24 | local<<17 | other, placed in the bucket's
// fixed slot [j*CAP, j*CAP+CAP).
// ---------------------------------------------------------------------------
__global__ __launch_bounds__(256) void prep_kernel(
    const float* __restrict__ f, unsigned int* __restrict__ fb16u,
    const float* __restrict__ w_in, const float* __restrict__ w_hid,
    const float* __restrict__ w_out, unsigned short* __restrict__ wp,
    const int* __restrict__ esrc, const int* __restrict__ edst,
    const float* __restrict__ ew, int* __restrict__ bcur,
    u64* __restrict__ adj64) {
    int b = blockIdx.x;
    if (b < BS_NB) {
        __shared__ int cnt[NB];
        __shared__ int bas[NB];
        int t = threadIdx.x;
        for (int j = t; j < NB; j += 256) cnt[j] = 0;
        __syncthreads();
        int base = b * BCHUNK;
        int nE = min(BCHUNK, EE - base);     // 16384 or 10752, both %8 == 0
        // pass 1: bucket histogram (indices only; window becomes L2-hot)
#pragma unroll
        for (int k = 0; k < 8; k++) {
            int i = k * 2048 + t * 8;
            if (i < nE) {
                int4 sa = *(const int4*)&esrc[base + i];
                int4 sb = *(const int4*)&esrc[base + i + 4];
                int4 da = *(const int4*)&edst[base + i];
                int4 db = *(const int4*)&edst[base + i + 4];
                atomicAdd(&cnt[sa.x >> 7], 1); atomicAdd(&cnt[da.x >> 7], 1);
                atomicAdd(&cnt[sa.y >> 7], 1); atomicAdd(&cnt[da.y >> 7], 1);
                atomicAdd(&cnt[sa.z >> 7], 1); atomicAdd(&cnt[da.z >> 7], 1);
                atomicAdd(&cnt[sa.w >> 7], 1); atomicAdd(&cnt[da.w >> 7], 1);
                atomicAdd(&cnt[sb.x >> 7], 1); atomicAdd(&cnt[db.x >> 7], 1);
                atomicAdd(&cnt[sb.y >> 7], 1); atomicAdd(&cnt[db.y >> 7], 1);
                atomicAdd(&cnt[sb.z >> 7], 1); atomicAdd(&cnt[db.z >> 7], 1);
                atomicAdd(&cnt[sb.w >> 7], 1); atomicAdd(&cnt[db.w >> 7], 1);
            }
        }
        __syncthreads();
        for (int j = t; j < NB; j += 256) {
            int c = cnt[j];
            bas[j] = (c ? atomicAdd(&bcur[j], c) : 0) + j * CAP;
            cnt[j] = 0;                      // reuse as intra-run cursor
        }
        __syncthreads();
        // pass 2: placement (re-read L2-hot window incl. weights)
#pragma unroll
        for (int k = 0; k < 8; k++) {
            int i = k * 2048 + t * 8;
            if (i < nE) {
                int4 sa = *(const int4*)&esrc[base + i];
                int4 sb = *(const int4*)&esrc[base + i + 4];
                int4 da = *(const int4*)&edst[base + i];
                int4 db = *(const int4*)&edst[base + i + 4];
                float4 wa = *(const float4*)&ew[base + i];
                float4 wb = *(const float4*)&ew[base + i + 4];
#define EMIT(s, d, w)                                                         \
                {                                                             \
                    u64 wb64 = ((u64)__float_as_uint(w)) << 32;               \
                    int p1 = bas[(s) >> 7] + atomicAdd(&cnt[(s) >> 7], 1);    \
                    adj64[p1] = wb64 | SIDE_BIT | (unsigned)((d) | (((s) & 127) << 17)); \
                    int p2 = bas[(d) >> 7] + atomicAdd(&cnt[(d) >> 7], 1);    \
                    adj64[p2] = wb64 | (unsigned)((s) | (((d) & 127) << 17)); \
                }
                EMIT(sa.x, da.x, wa.x) EMIT(sa.y, da.y, wa.y)
                EMIT(sa.z, da.z, wa.z) EMIT(sa.w, da.w, wa.w)
                EMIT(sb.x, db.x, wb.x) EMIT(sb.y, db.y, wb.y)
                EMIT(sb.z, db.z, wb.z) EMIT(sb.w, db.w, wb.w)
#undef EMIT
            }
        }
    } else if (b < BS_NB + PRE_NB) {
        int i = (b - BS_NB) * 256 + threadIdx.x;    // < 800000 exactly
        float4 v0 = *(const float4*)&f[i * 8];
        float4 v1 = *(const float4*)&f[i * 8 + 4];
        uint4 w;
        w.x = pack2(v0.x, v0.y);
        w.y = pack2(v0.z, v0.w);
        w.z = pack2(v1.x, v1.y);
        w.w = pack2(v1.z, v1.w);
        *(uint4*)&fb16u[i * 4] = w;
    } else {
        int i = (b - BS_NB - PRE_NB) * 256 + threadIdx.x;  // < 5*4096 exactly
        int l = i >> 12, idx = i & 4095;
        int n = idx >> 6, k = idx & 63;
        const float* W = (l == 0) ? w_in : (l < 4 ? w_hid + (l - 1) * 4096 : w_out);
        wp[i] = f2bf(W[k * 64 + n]);
    }
}

// ---------------------------------------------------------------------------
// Cooperative bucket build (histo + scatter fused, entries LDS-resident
// across a grid sync). Phase 1: load span -> LDS, per-node histogram
// (total + src-side = out-degree), prefix, write node_offs/node_end/deg
// (each 64B deg line owned by exactly one block). threadfence + grid.sync
// makes deg[] device-visible. Phase 2: scatter from LDS -> adj4 with
// q = w / outdeg(src); dst-side reads deg[other] (fresh, post-sync).
// LDS = 4608*8 + 2KB = 38.9 KB -> 4 blocks/CU -> 1024 >= 782 co-resident.
// ---------------------------------------------------------------------------
__global__ __launch_bounds__(256) void bucket_build(
    const int* __restrict__ bcur, const u64* __restrict__ adj64,
    int* __restrict__ node_offs, int* __restrict__ node_end,
    int* __restrict__ deg, unsigned int* __restrict__ adj4) {
    __shared__ u64 ent[CAP];
    __shared__ int cnt_tot[128], cnt_src[128], sc[128], cur[128];
    cg::grid_group grid = cg::this_grid();
    int t = threadIdx.x, b = blockIdx.x;
    if (t < 128) { cnt_tot[t] = 0; cnt_src[t] = 0; }
    __syncthreads();
    int used = bcur[b];
    int gstart = b * CAP;
    for (int i = t; i < used; i += 256) {
        u64 e = adj64[gstart + i];
        ent[i] = e;
        unsigned lo = (unsigned)e;
        int local = (lo >> 17) & 127;
        atomicAdd(&cnt_tot[local], 1);
        if (lo & SIDE_BIT) atomicAdd(&cnt_src[local], 1);
    }
    __syncthreads();
    if (t < 128) sc[t] = cnt_tot[t];
    __syncthreads();
    for (int o = 1; o < 128; o <<= 1) {
        int x = 0;
        if (t < 128 && t >= o) x = sc[t - o];
        __syncthreads();
        if (t < 128) sc[t] += x;
        __syncthreads();
    }
    if (t < 128) {
        int n = b * 128 + t;
        int st = gstart + sc[t] - cnt_tot[t];
        cur[t] = st;
        if (n < NN) {
            node_offs[n] = st;                 // exclusive, gapped
            node_end[n]  = gstart + sc[t];
            deg[n] = cnt_src[t];
        }
    }
    __threadfence();
    grid.sync();
    for (int i = t; i < used; i += 256) {
        u64 e = ent[i];
        unsigned lo = (unsigned)e;
        int local = (lo >> 17) & 127;
        unsigned other = lo & 0x1FFFFu;
        float w = __uint_as_float((unsigned)(e >> 32));
        float dv = (lo & SIDE_BIT) ? (float)cnt_src[local] : (float)deg[other];
        float q = w / dv;
        unsigned q15 = (unsigned)(q * 32768.f + 0.5f);
        if (q15 > 32767u) q15 = 32767u;
        int p = atomicAdd(&cur[local], 1);
        adj4[p] = (q15 << 17) | other;
    }
}

// ---------------------------------------------------------------------------
// Gather transport (measured HBM-random floor ~90us, UNCHANGED): one wave
// per node, OCTANT (8 lanes) per entry, uint4 row loads, 4-deep unroll.
// ---------------------------------------------------------------------------
#define ACC8(q, r)                                          \
    a0 = fmaf(q, __uint_as_float(r.x << 16), a0);           \
    a1 = fmaf(q, __uint_as_float(r.x & 0xFFFF0000u), a1);   \
    a2 = fmaf(q, __uint_as_float(r.y << 16), a2);           \
    a3 = fmaf(q, __uint_as_float(r.y & 0xFFFF0000u), a3);   \
    a4 = fmaf(q, __uint_as_float(r.z << 16), a4);           \
    a5 = fmaf(q, __uint_as_float(r.z & 0xFFFF0000u), a5);   \
    a6 = fmaf(q, __uint_as_float(r.w << 16), a6);           \
    a7 = fmaf(q, __uint_as_float(r.w & 0xFFFF0000u), a7);   \
    qs += q;

__global__ __launch_bounds__(256) void gather_kernel(
    const unsigned int* __restrict__ fb16u, const int* __restrict__ node_offs,
    const int* __restrict__ node_end,
    const unsigned int* __restrict__ adj, const float* __restrict__ xi,
    float* __restrict__ trans) {
    const float QS = 1.f / 32768.f;
    int lane = threadIdx.x & 63;
    int n = blockIdx.x * 4 + (threadIdx.x >> 6);
    if (n >= NN) return;
    int c = lane & 7;      // uint4 column: bins 8c..8c+7
    int qt = lane >> 3;    // octant index: entry j+qt
    int j = node_offs[n];
    int end = node_end[n];
    float a0 = 0.f, a1 = 0.f, a2 = 0.f, a3 = 0.f;
    float a4 = 0.f, a5 = 0.f, a6 = 0.f, a7 = 0.f, qs = 0.f;
    for (; j + 32 <= end; j += 32) {
        unsigned e0 = __builtin_nontemporal_load(&adj[j + qt]);
        unsigned e1 = __builtin_nontemporal_load(&adj[j + 8 + qt]);
        unsigned e2 = __builtin_nontemporal_load(&adj[j + 16 + qt]);
        unsigned e3 = __builtin_nontemporal_load(&adj[j + 24 + qt]);
        uint4 r0 = *(const uint4*)&fb16u[(e0 & 0x1FFFFu) * 32 + c * 4];
        uint4 r1 = *(const uint4*)&fb16u[(e1 & 0x1FFFFu) * 32 + c * 4];
        uint4 r2 = *(const uint4*)&fb16u[(e2 & 0x1FFFFu) * 32 + c * 4];
        uint4 r3 = *(const uint4*)&fb16u[(e3 & 0x1FFFFu) * 32 + c * 4];
        float q0 = (float)(e0 >> 17) * QS;
        float q1 = (float)(e1 >> 17) * QS;
        float q2 = (float)(e2 >> 17) * QS;
        float q3 = (float)(e3 >> 17) * QS;
        ACC8(q0, r0)
        ACC8(q1, r1)
        ACC8(q2, r2)
        ACC8(q3, r3)
    }
    for (; j + 8 <= end; j += 8) {
        unsigned e = __builtin_nontemporal_load(&adj[j + qt]);
        uint4 r = *(const uint4*)&fb16u[(e & 0x1FFFFu) * 32 + c * 4];
        float q = (float)(e >> 17) * QS;
        ACC8(q, r)
    }
    if (j < end) {                       // tail: 1..7 entries, octant-guarded
        int idx = j + qt;
        bool ok = idx < end;
        unsigned e = ok ? adj[idx] : 0u;
        uint4 r = *(const uint4*)&fb16u[(e & 0x1FFFFu) * 32 + c * 4];
        float q = ok ? (float)(e >> 17) * QS : 0.f;
        ACC8(q, r)
    }
#define RED3(x) x += __shfl_xor(x, 8); x += __shfl_xor(x, 16); x += __shfl_xor(x, 32)
    RED3(a0); RED3(a1); RED3(a2); RED3(a3);
    RED3(a4); RED3(a5); RED3(a6); RED3(a7); RED3(qs);
    if (qt == 0) {                       // lanes 0..7 hold bins 8c..8c+7
        uint4 rn = *(const uint4*)&fb16u[n * 32 + c * 4];
        float4 x0 = *(const float4*)&xi[c * 8];
        float4 x1 = *(const float4*)&xi[c * 8 + 4];
        f32x4 o0, o1;
        o0.x = x0.x * (a0 - qs * __uint_as_float(rn.x << 16));
        o0.y = x0.y * (a1 - qs * __uint_as_float(rn.x & 0xFFFF0000u));
        o0.z = x0.z * (a2 - qs * __uint_as_float(rn.y << 16));
        o0.w = x0.w * (a3 - qs * __uint_as_float(rn.y & 0xFFFF0000u));
        o1.x = x1.x * (a4 - qs * __uint_as_float(rn.z << 16));
        o1.y = x1.y * (a5 - qs * __uint_as_float(rn.z & 0xFFFF0000u));
        o1.z = x1.z * (a6 - qs * __uint_as_float(rn.w << 16));
        o1.w = x1.w * (a7 - qs * __uint_as_float(rn.w & 0xFFFF0000u));
        __builtin_nontemporal_store(o0, (f32x4*)&trans[n * 64 + c * 8]);
        __builtin_nontemporal_store(o1, (f32x4*)&trans[n * 64 + c * 8 + 4]);
    }
}

// ---------------------------------------------------------------------------
// MFMA node kernel (proven, unchanged): 256 thr / 4 waves / 128 nodes,
// barrier-free layer loop, wave-private act rows, pre-transposed bf16 weights.
// ---------------------------------------------------------------------------
__global__ __launch_bounds__(256) void node_kernel(
    const unsigned short* __restrict__ fb16, const float* __restrict__ f,
    const float* __restrict__ macro_u, const float* __restrict__ source,
    const float* __restrict__ xi, const unsigned short* __restrict__ wp,
    const float* __restrict__ b_in, const float* __restrict__ b_hid,
    const float* __restrict__ b_out,
    const float* __restrict__ trans, float* __restrict__ out) {
    __shared__ __attribute__((aligned(16))) unsigned short act[128 * ACT_S];
    __shared__ float s0s[128], s1s[128], us[128], xif[64];

    const int t = threadIdx.x;
    const int wid = t >> 6;
    const int lane = t & 63;
    const int m = lane & 15;
    const int quad = lane >> 4;
    const int nodeBase = blockIdx.x * 128;
    const int gbase = nodeBase * 64;

    if (t < 128) {
        int n = nodeBase + t;
        us[t] = (n < NN) ? macro_u[n] : 0.f;
    }
    if (t < 64) xif[t] = xi[t];

#pragma unroll
    for (int i = 0; i < 8; i++) {
        int r = wid * 32 + i * 4 + (lane >> 4);
        int c = (lane & 15) * 4;
        uint2 v = {0u, 0u};
        if (nodeBase + r < NN) v = *(const uint2*)&fb16[gbase + r * 64 + c];
        *(uint2*)&act[r * ACT_S + c] = v;
    }

    const int rowbase = wid * 32;

    for (int l = 0; l < 5; l++) {
        const unsigned short* W = wp + l * 4096;
        const float* B = (l == 0) ? b_in : (l < 4 ? b_hid + (l - 1) * 64 : b_out);

        short8 Af[2][2], Bf[4][2];
#pragma unroll
        for (int rt = 0; rt < 2; rt++)
#pragma unroll
            for (int kk = 0; kk < 2; kk++)
                Af[rt][kk] = *(const short8*)&act[(rowbase + rt * 16 + m) * ACT_S + kk * 32 + quad * 8];
#pragma unroll
        for (int ct = 0; ct < 4; ct++)
#pragma unroll
            for (int kk = 0; kk < 2; kk++)
                Bf[ct][kk] = *(const short8*)&W[(ct * 16 + m) * 64 + kk * 32 + quad * 8];

        f32x4 acc[2][4];
#pragma unroll
        for (int rt = 0; rt < 2; rt++)
#pragma unroll
            for (int ct = 0; ct < 4; ct++) {
                acc[rt][ct] = (f32x4){0.f, 0.f, 0.f, 0.f};
                acc[rt][ct] = __builtin_amdgcn_mfma_f32_16x16x32_bf16(Af[rt][0], Bf[ct][0], acc[rt][ct], 0, 0, 0);
                acc[rt][ct] = __builtin_amdgcn_mfma_f32_16x16x32_bf16(Af[rt][1], Bf[ct][1], acc[rt][ct], 0, 0, 0);
            }

#pragma unroll
        for (int rt = 0; rt < 2; rt++)
#pragma unroll
            for (int ct = 0; ct < 4; ct++) {
                float bv = B[ct * 16 + m];
#pragma unroll
                for (int r = 0; r < 4; r++) {
                    int row = rowbase + rt * 16 + quad * 4 + r;
                    float val = acc[rt][ct][r] + bv;
                    val = (l < 4) ? fmaxf(val, 0.f) : tanhf(val);
                    act[row * ACT_S + ct * 16 + m] = f2bf(val);
                }
            }
    }
    __syncthreads();

    if (t < 128) {
        float u = us[t];
        float v0 = 0.f, v1 = 0.f, sxs2 = 0.f, sxi = 0.f;
        const short8* rp = (const short8*)&act[t * ACT_S];
#pragma unroll
        for (int c = 0; c < 8; c++) {
            short8 v = rp[c];
#pragma unroll
            for (int jj = 0; jj < 8; jj++) {
                float om = bf2f((unsigned short)v[jj]);
                float xv = xif[c * 8 + jj];
                float xs = xv + u;
                v0 += om;
                v1 += xs * om;
                sxs2 += xs * xs;
                sxi += xv;
            }
        }
        v0 *= WQc;
        v1 *= WQc;
        float c00 = WQc + REGc;
        float c01 = WQc * WQc * (sxi + 64.f * u);
        float c11 = WQc * WQc * sxs2 + REGc;
        float det = c00 * c11 - c01 * c01;
        float inv = 1.0f / det;
        s0s[t] = (c11 * v0 - c01 * v1) * inv;
        s1s[t] = (c00 * v1 - c01 * v0) * inv;
    }
    __syncthreads();

#pragma unroll
    for (int i = 0; i < 8; i++) {
        int e = (i * 256 + t) * 4;
        int nl = e >> 6;
        if (nodeBase + nl < NN) {
            int g = gbase + e;
            int c0 = e & 63;
            float4 fv = *(const float4*)&f[g];
            float4 sv = *(const float4*)&source[g];
            float4 tv = *(const float4*)&trans[g];
            float uu = us[nl];
            float sv0 = s0s[nl], sv1 = s1s[nl];
            float4 ov;
            float* ovp = (float*)&ov;
            const float* fp = (const float*)&fv;
            const float* sp = (const float*)&sv;
            const float* tp = (const float*)&tv;
#pragma unroll
            for (int jj = 0; jj < 4; jj++) {
                float om = bf2f(act[nl * ACT_S + c0 + jj]);
                float xs = xif[c0 + jj] + uu;
                float omst = om - WQc * (sv0 + xs * sv1);
                float val = fmaxf(fp[jj], 0.f) + DTc * (sp[jj] + omst - tp[jj]);
                ovp[jj] = fmaxf(val, 0.f);
            }
            *(float4*)&out[g] = ov;
        }
    }
}

extern "C" void kernel_launch(void* const* d_in, const int* in_sizes, int n_in,
                              void* d_out, int out_size, void* d_ws, size_t ws_size,
                              hipStream_t stream) {
    const float* f       = (const float*)d_in[0];
    const float* macro_u = (const float*)d_in[1];
    const float* source  = (const float*)d_in[2];
    const int*   esrc    = (const int*)d_in[3];
    const int*   edst    = (const int*)d_in[4];
    const float* ew      = (const float*)d_in[5];
    const float* xi      = (const float*)d_in[6];
    const float* w_in    = (const float*)d_in[7];
    const float* b_in    = (const float*)d_in[8];
    const float* w_hid   = (const float*)d_in[9];
    const float* b_hid   = (const float*)d_in[10];
    const float* w_out   = (const float*)d_in[11];
    const float* b_out   = (const float*)d_in[12];
    float* out = (float*)d_out;

    // workspace layout (8-byte entries first)
    u64* adj64 = (u64*)d_ws;                                   // NB*CAP u64 = 28.8 MB (gapped)
    unsigned int* adj4 = (unsigned int*)(adj64 + (size_t)NB * CAP);  // NB*CAP u32 = 14.4 MB (gapped)
    int* deg   = (int*)(adj4 + (size_t)NB * CAP);              // NN (plain stores)
    int* node_offs = deg + NN;                                 // NN (gapped starts)
    int* node_end  = node_offs + NN;                           // NN (gapped ends)
    int* bcur  = node_end + NN;                                // NB used-counts (memset 0)
    float* trans = (float*)(bcur + 784);                       // NN*64
    unsigned short* fb16 = (unsigned short*)(trans + (size_t)NN * 64);  // NN*64 bf16
    unsigned short* wp = fb16 + (size_t)NN * 64;               // 5*4096

    hipMemsetAsync(bcur, 0, 784 * sizeof(int), stream);

    prep_kernel<<<BS_NB + PRE_NB + WP_NB, 256, 0, stream>>>(
        f, (unsigned int*)fb16, w_in, w_hid, w_out, wp, esrc, edst, ew, bcur, adj64);

    {
        void* args[] = {(void*)&bcur, (void*)&adj64, (void*)&node_offs,
                        (void*)&node_end, (void*)&deg, (void*)&adj4};
        hipLaunchCooperativeKernel((void*)bucket_build, dim3(NB), dim3(256),
                                   args, 0, stream);
    }

    gather_kernel<<<(NN + 3) / 4, 256, 0, stream>>>((const unsigned int*)fb16,
                                                    node_offs, node_end, adj4, xi, trans);
    node_kernel<<<(NN + 127) / 128, 256, 0, stream>>>(
        fb16, f, macro_u, source, xi, wp, b_in, b_hid, b_out, trans, out);
}

// Round 12
// 320.112 us; speedup vs baseline: 1.3448x; 1.3448x over previous
//
#include <hip/hip_runtime.h>

#define NN 100000
#define EE 1600000
#define DTc 0.1f
#define REGc 1e-6f
#define WQc (1.0f / 64.0f)

#define NB 782              // ceil(NN/128) buckets of 128 nodes
#define CAP 4736            // fixed bucket capacity (mean 4092 + 10 sigma)
#define BCHUNK 16384        // edges per bin block (big runs -> coalesced writes)
#define BS_NB 98            // ceil(EE/BCHUNK)
#define ACT_S 72            // padded LDS row stride (bf16) in node_kernel
#define PRE_NB 3125         // NN*64 floats / (256 thr * 8 floats) exact
#define WP_NB 80            // 5*4096/256 exact
#define SIDE_BIT (1u << 24) // entry is src-side (local == src of the edge)

typedef unsigned long long u64;
typedef __attribute__((ext_vector_type(8))) short short8;
typedef __attribute__((ext_vector_type(4))) float f32x4;

__device__ __forceinline__ unsigned short f2bf(float x) {
    unsigned u = __float_as_uint(x);
    unsigned r = (u + 0x7fffu + ((u >> 16) & 1u)) >> 16;   // RNE
    return (unsigned short)r;
}
__device__ __forceinline__ float bf2f(unsigned short s) {
    return __uint_as_float(((unsigned)s) << 16);
}
__device__ __forceinline__ unsigned pack2(float a, float b) {
    return (unsigned)f2bf(fmaxf(a, 0.f)) | ((unsigned)f2bf(fmaxf(b, 0.f)) << 16);
}

// ---------------------------------------------------------------------------
// Mega prep (R10 structure; bin phase upgraded to BCHUNK=16384 2-pass for
// write coalescing: per-(block,bucket) runs ~42 entries = ~full cachelines,
// reservation atomics 611K -> 76K). Bin blocks FIRST so their latency hides
// under the 3205 streaming blocks behind them.
//   [0, BS_NB)          -> self-reserving binned scatter of 16384 edges
//   [BS_NB, +PRE_NB)    -> f+ = relu(f) as bf16, 8 floats/thread
//   [BS_NB+PRE_NB, ..)  -> transposed bf16 weights
// entry = (f32 w)<<32 | side<<24 | local<<17 | other, in bucket slot
// [j*CAP, j*CAP+CAP).
// ---------------------------------------------------------------------------
__global__ __launch_bounds__(256) void prep_kernel(
    const float* __restrict__ f, unsigned int* __restrict__ fb16u,
    const float* __restrict__ w_in, const float* __restrict__ w_hid,
    const float* __restrict__ w_out, unsigned short* __restrict__ wp,
    const int* __restrict__ esrc, const int* __restrict__ edst,
    const float* __restrict__ ew, int* __restrict__ bcur,
    u64* __restrict__ adj64) {
    int b = blockIdx.x;
    if (b < BS_NB) {
        __shared__ int cnt[NB];
        __shared__ int bas[NB];
        int t = threadIdx.x;
        for (int j = t; j < NB; j += 256) cnt[j] = 0;
        __syncthreads();
        int base = b * BCHUNK;
        int nE = min(BCHUNK, EE - base);     // 16384 or 10752, both %8 == 0
        // pass 1: bucket histogram (indices only; window becomes L2-hot)
#pragma unroll
        for (int k = 0; k < 8; k++) {
            int i = k * 2048 + t * 8;
            if (i < nE) {
                int4 sa = *(const int4*)&esrc[base + i];
                int4 sb = *(const int4*)&esrc[base + i + 4];
                int4 da = *(const int4*)&edst[base + i];
                int4 db = *(const int4*)&edst[base + i + 4];
                atomicAdd(&cnt[sa.x >> 7], 1); atomicAdd(&cnt[da.x >> 7], 1);
                atomicAdd(&cnt[sa.y >> 7], 1); atomicAdd(&cnt[da.y >> 7], 1);
                atomicAdd(&cnt[sa.z >> 7], 1); atomicAdd(&cnt[da.z >> 7], 1);
                atomicAdd(&cnt[sa.w >> 7], 1); atomicAdd(&cnt[da.w >> 7], 1);
                atomicAdd(&cnt[sb.x >> 7], 1); atomicAdd(&cnt[db.x >> 7], 1);
                atomicAdd(&cnt[sb.y >> 7], 1); atomicAdd(&cnt[db.y >> 7], 1);
                atomicAdd(&cnt[sb.z >> 7], 1); atomicAdd(&cnt[db.z >> 7], 1);
                atomicAdd(&cnt[sb.w >> 7], 1); atomicAdd(&cnt[db.w >> 7], 1);
            }
        }
        __syncthreads();
        for (int j = t; j < NB; j += 256) {
            int c = cnt[j];
            bas[j] = (c ? atomicAdd(&bcur[j], c) : 0) + j * CAP;
            cnt[j] = 0;                      // reuse as intra-run cursor
        }
        __syncthreads();
        // pass 2: placement (re-read L2-hot window incl. weights)
#pragma unroll
        for (int k = 0; k < 8; k++) {
            int i = k * 2048 + t * 8;
            if (i < nE) {
                int4 sa = *(const int4*)&esrc[base + i];
                int4 sb = *(const int4*)&esrc[base + i + 4];
                int4 da = *(const int4*)&edst[base + i];
                int4 db = *(const int4*)&edst[base + i + 4];
                float4 wa = *(const float4*)&ew[base + i];
                float4 wb = *(const float4*)&ew[base + i + 4];
#define EMIT(s, d, w)                                                         \
                {                                                             \
                    u64 wb64 = ((u64)__float_as_uint(w)) << 32;               \
                    int p1 = bas[(s) >> 7] + atomicAdd(&cnt[(s) >> 7], 1);    \
                    adj64[p1] = wb64 | SIDE_BIT | (unsigned)((d) | (((s) & 127) << 17)); \
                    int p2 = bas[(d) >> 7] + atomicAdd(&cnt[(d) >> 7], 1);    \
                    adj64[p2] = wb64 | (unsigned)((s) | (((d) & 127) << 17)); \
                }
                EMIT(sa.x, da.x, wa.x) EMIT(sa.y, da.y, wa.y)
                EMIT(sa.z, da.z, wa.z) EMIT(sa.w, da.w, wa.w)
                EMIT(sb.x, db.x, wb.x) EMIT(sb.y, db.y, wb.y)
                EMIT(sb.z, db.z, wb.z) EMIT(sb.w, db.w, wb.w)
#undef EMIT
            }
        }
    } else if (b < BS_NB + PRE_NB) {
        int i = (b - BS_NB) * 256 + threadIdx.x;    // < 800000 exactly
        float4 v0 = *(const float4*)&f[i * 8];
        float4 v1 = *(const float4*)&f[i * 8 + 4];
        uint4 w;
        w.x = pack2(v0.x, v0.y);
        w.y = pack2(v0.z, v0.w);
        w.z = pack2(v1.x, v1.y);
        w.w = pack2(v1.z, v1.w);
        *(uint4*)&fb16u[i * 4] = w;
    } else {
        int i = (b - BS_NB - PRE_NB) * 256 + threadIdx.x;  // < 5*4096 exactly
        int l = i >> 12, idx = i & 4095;
        int n = idx >> 6, k = idx & 63;
        const float* W = (l == 0) ? w_in : (l < 4 ? w_hid + (l - 1) * 4096 : w_out);
        wp[i] = f2bf(W[k * 64 + n]);
    }
}

// ---------------------------------------------------------------------------
// Bucket histogram (R10-proven, unchanged): counts entries & src-side
// entries per local node; node_offs/node_end in GAPPED adj4 space (base
// b*CAP); deg[n] = out-degree via src-side count. Plain stores only.
// ---------------------------------------------------------------------------
__global__ __launch_bounds__(256) void bucket_histo(
    const int* __restrict__ bcur, const u64* __restrict__ adj64,
    int* __restrict__ node_offs, int* __restrict__ node_end,
    int* __restrict__ deg) {
    __shared__ int cnt_tot[128], cnt_src[128], sc[128];
    int t = threadIdx.x, b = blockIdx.x;
    if (t < 128) { cnt_tot[t] = 0; cnt_src[t] = 0; }
    __syncthreads();
    int used = bcur[b];
    int gstart = b * CAP;
    for (int i = t; i < used; i += 256) {
        unsigned lo = (unsigned)adj64[gstart + i];
        int local = (lo >> 17) & 127;
        atomicAdd(&cnt_tot[local], 1);
        if (lo & SIDE_BIT) atomicAdd(&cnt_src[local], 1);
    }
    __syncthreads();
    if (t < 128) sc[t] = cnt_tot[t];
    __syncthreads();
    for (int o = 1; o < 128; o <<= 1) {
        int x = 0;
        if (t < 128 && t >= o) x = sc[t - o];
        __syncthreads();
        if (t < 128) sc[t] += x;
        __syncthreads();
    }
    if (t < 128) {
        int n = b * 128 + t;
        if (n < NN) {
            node_offs[n] = gstart + sc[t] - cnt_tot[t];   // exclusive, gapped
            node_end[n]  = gstart + sc[t];
            deg[n] = cnt_src[t];
        }
    }
}

// ---------------------------------------------------------------------------
// Bucket scatter (R10-proven, unchanged): q = w / outdeg(src); src-side deg
// from LDS, dst-side deg[other] (400 KB, L2-hot). Gapped per-node CSR adj4.
// ---------------------------------------------------------------------------
__global__ __launch_bounds__(256) void bucket_scatter(
    const int* __restrict__ bcur, const u64* __restrict__ adj64,
    const int* __restrict__ node_offs, const int* __restrict__ deg,
    unsigned int* __restrict__ adj4) {
    __shared__ int cur[128];
    __shared__ float ldeg[128];
    int t = threadIdx.x, b = blockIdx.x;
    if (t < 128) {
        int n = b * 128 + t;
        cur[t] = (n < NN) ? node_offs[n] : 0;
        ldeg[t] = (n < NN) ? (float)deg[n] : 1.f;
    }
    __syncthreads();
    int used = bcur[b];
    int gstart = b * CAP;
    for (int i = t; i < used; i += 256) {
        u64 e = adj64[gstart + i];
        unsigned lo = (unsigned)e;
        int local = (lo >> 17) & 127;
        unsigned other = lo & 0x1FFFFu;
        float w = __uint_as_float((unsigned)(e >> 32));
        float dv = (lo & SIDE_BIT) ? ldeg[local] : (float)deg[other];
        float q = w / dv;
        unsigned q15 = (unsigned)(q * 32768.f + 0.5f);
        if (q15 > 32767u) q15 = 32767u;
        int p = atomicAdd(&cur[local], 1);
        adj4[p] = (q15 << 17) | other;
    }
}

// ---------------------------------------------------------------------------
// Gather transport (measured HBM-random floor ~90us, UNCHANGED): one wave
// per node, OCTANT (8 lanes) per entry, uint4 row loads, 4-deep unroll.
// ---------------------------------------------------------------------------
#define ACC8(q, r)                                          \
    a0 = fmaf(q, __uint_as_float(r.x << 16), a0);           \
    a1 = fmaf(q, __uint_as_float(r.x & 0xFFFF0000u), a1);   \
    a2 = fmaf(q, __uint_as_float(r.y << 16), a2);           \
    a3 = fmaf(q, __uint_as_float(r.y & 0xFFFF0000u), a3);   \
    a4 = fmaf(q, __uint_as_float(r.z << 16), a4);           \
    a5 = fmaf(q, __uint_as_float(r.z & 0xFFFF0000u), a5);   \
    a6 = fmaf(q, __uint_as_float(r.w << 16), a6);           \
    a7 = fmaf(q, __uint_as_float(r.w & 0xFFFF0000u), a7);   \
    qs += q;

__global__ __launch_bounds__(256) void gather_kernel(
    const unsigned int* __restrict__ fb16u, const int* __restrict__ node_offs,
    const int* __restrict__ node_end,
    const unsigned int* __restrict__ adj, const float* __restrict__ xi,
    float* __restrict__ trans) {
    const float QS = 1.f / 32768.f;
    int lane = threadIdx.x & 63;
    int n = blockIdx.x * 4 + (threadIdx.x >> 6);
    if (n >= NN) return;
    int c = lane & 7;      // uint4 column: bins 8c..8c+7
    int qt = lane >> 3;    // octant index: entry j+qt
    int j = node_offs[n];
    int end = node_end[n];
    float a0 = 0.f, a1 = 0.f, a2 = 0.f, a3 = 0.f;
    float a4 = 0.f, a5 = 0.f, a6 = 0.f, a7 = 0.f, qs = 0.f;
    for (; j + 32 <= end; j += 32) {
        unsigned e0 = __builtin_nontemporal_load(&adj[j + qt]);
        unsigned e1 = __builtin_nontemporal_load(&adj[j + 8 + qt]);
        unsigned e2 = __builtin_nontemporal_load(&adj[j + 16 + qt]);
        unsigned e3 = __builtin_nontemporal_load(&adj[j + 24 + qt]);
        uint4 r0 = *(const uint4*)&fb16u[(e0 & 0x1FFFFu) * 32 + c * 4];
        uint4 r1 = *(const uint4*)&fb16u[(e1 & 0x1FFFFu) * 32 + c * 4];
        uint4 r2 = *(const uint4*)&fb16u[(e2 & 0x1FFFFu) * 32 + c * 4];
        uint4 r3 = *(const uint4*)&fb16u[(e3 & 0x1FFFFu) * 32 + c * 4];
        float q0 = (float)(e0 >> 17) * QS;
        float q1 = (float)(e1 >> 17) * QS;
        float q2 = (float)(e2 >> 17) * QS;
        float q3 = (float)(e3 >> 17) * QS;
        ACC8(q0, r0)
        ACC8(q1, r1)
        ACC8(q2, r2)
        ACC8(q3, r3)
    }
    for (; j + 8 <= end; j += 8) {
        unsigned e = __builtin_nontemporal_load(&adj[j + qt]);
        uint4 r = *(const uint4*)&fb16u[(e & 0x1FFFFu) * 32 + c * 4];
        float q = (float)(e >> 17) * QS;
        ACC8(q, r)
    }
    if (j < end) {                       // tail: 1..7 entries, octant-guarded
        int idx = j + qt;
        bool ok = idx < end;
        unsigned e = ok ? adj[idx] : 0u;
        uint4 r = *(const uint4*)&fb16u[(e & 0x1FFFFu) * 32 + c * 4];
        float q = ok ? (float)(e >> 17) * QS : 0.f;
        ACC8(q, r)
    }
#define RED3(x) x += __shfl_xor(x, 8); x += __shfl_xor(x, 16); x += __shfl_xor(x, 32)
    RED3(a0); RED3(a1); RED3(a2); RED3(a3);
    RED3(a4); RED3(a5); RED3(a6); RED3(a7); RED3(qs);
    if (qt == 0) {                       // lanes 0..7 hold bins 8c..8c+7
        uint4 rn = *(const uint4*)&fb16u[n * 32 + c * 4];
        float4 x0 = *(const float4*)&xi[c * 8];
        float4 x1 = *(const float4*)&xi[c * 8 + 4];
        f32x4 o0, o1;
        o0.x = x0.x * (a0 - qs * __uint_as_float(rn.x << 16));
        o0.y = x0.y * (a1 - qs * __uint_as_float(rn.x & 0xFFFF0000u));
        o0.z = x0.z * (a2 - qs * __uint_as_float(rn.y << 16));
        o0.w = x0.w * (a3 - qs * __uint_as_float(rn.y & 0xFFFF0000u));
        o1.x = x1.x * (a4 - qs * __uint_as_float(rn.z << 16));
        o1.y = x1.y * (a5 - qs * __uint_as_float(rn.z & 0xFFFF0000u));
        o1.z = x1.z * (a6 - qs * __uint_as_float(rn.w << 16));
        o1.w = x1.w * (a7 - qs * __uint_as_float(rn.w & 0xFFFF0000u));
        __builtin_nontemporal_store(o0, (f32x4*)&trans[n * 64 + c * 8]);
        __builtin_nontemporal_store(o1, (f32x4*)&trans[n * 64 + c * 8 + 4]);
    }
}

// ---------------------------------------------------------------------------
// MFMA node kernel (proven, unchanged): 256 thr / 4 waves / 128 nodes,
// barrier-free layer loop, wave-private act rows, pre-transposed bf16 weights.
// ---------------------------------------------------------------------------
__global__ __launch_bounds__(256) void node_kernel(
    const unsigned short* __restrict__ fb16, const float* __restrict__ f,
    const float* __restrict__ macro_u, const float* __restrict__ source,
    const float* __restrict__ xi, const unsigned short* __restrict__ wp,
    const float* __restrict__ b_in, const float* __restrict__ b_hid,
    const float* __restrict__ b_out,
    const float* __restrict__ trans, float* __restrict__ out) {
    __shared__ __attribute__((aligned(16))) unsigned short act[128 * ACT_S];
    __shared__ float s0s[128], s1s[128], us[128], xif[64];

    const int t = threadIdx.x;
    const int wid = t >> 6;
    const int lane = t & 63;
    const int m = lane & 15;
    const int quad = lane >> 4;
    const int nodeBase = blockIdx.x * 128;
    const int gbase = nodeBase * 64;

    if (t < 128) {
        int n = nodeBase + t;
        us[t] = (n < NN) ? macro_u[n] : 0.f;
    }
    if (t < 64) xif[t] = xi[t];

#pragma unroll
    for (int i = 0; i < 8; i++) {
        int r = wid * 32 + i * 4 + (lane >> 4);
        int c = (lane & 15) * 4;
        uint2 v = {0u, 0u};
        if (nodeBase + r < NN) v = *(const uint2*)&fb16[gbase + r * 64 + c];
        *(uint2*)&act[r * ACT_S + c] = v;
    }

    const int rowbase = wid * 32;

    for (int l = 0; l < 5; l++) {
        const unsigned short* W = wp + l * 4096;
        const float* B = (l == 0) ? b_in : (l < 4 ? b_hid + (l - 1) * 64 : b_out);

        short8 Af[2][2], Bf[4][2];
#pragma unroll
        for (int rt = 0; rt < 2; rt++)
#pragma unroll
            for (int kk = 0; kk < 2; kk++)
                Af[rt][kk] = *(const short8*)&act[(rowbase + rt * 16 + m) * ACT_S + kk * 32 + quad * 8];
#pragma unroll
        for (int ct = 0; ct < 4; ct++)
#pragma unroll
            for (int kk = 0; kk < 2; kk++)
                Bf[ct][kk] = *(const short8*)&W[(ct * 16 + m) * 64 + kk * 32 + quad * 8];

        f32x4 acc[2][4];
#pragma unroll
        for (int rt = 0; rt < 2; rt++)
#pragma unroll
            for (int ct = 0; ct < 4; ct++) {
                acc[rt][ct] = (f32x4){0.f, 0.f, 0.f, 0.f};
                acc[rt][ct] = __builtin_amdgcn_mfma_f32_16x16x32_bf16(Af[rt][0], Bf[ct][0], acc[rt][ct], 0, 0, 0);
                acc[rt][ct] = __builtin_amdgcn_mfma_f32_16x16x32_bf16(Af[rt][1], Bf[ct][1], acc[rt][ct], 0, 0, 0);
            }

#pragma unroll
        for (int rt = 0; rt < 2; rt++)
#pragma unroll
            for (int ct = 0; ct < 4; ct++) {
                float bv = B[ct * 16 + m];
#pragma unroll
                for (int r = 0; r < 4; r++) {
                    int row = rowbase + rt * 16 + quad * 4 + r;
                    float val = acc[rt][ct][r] + bv;
                    val = (l < 4) ? fmaxf(val, 0.f) : tanhf(val);
                    act[row * ACT_S + ct * 16 + m] = f2bf(val);
                }
            }
    }
    __syncthreads();

    if (t < 128) {
        float u = us[t];
        float v0 = 0.f, v1 = 0.f, sxs2 = 0.f, sxi = 0.f;
        const short8* rp = (const short8*)&act[t * ACT_S];
#pragma unroll
        for (int c = 0; c < 8; c++) {
            short8 v = rp[c];
#pragma unroll
            for (int jj = 0; jj < 8; jj++) {
                float om = bf2f((unsigned short)v[jj]);
                float xv = xif[c * 8 + jj];
                float xs = xv + u;
                v0 += om;
                v1 += xs * om;
                sxs2 += xs * xs;
                sxi += xv;
            }
        }
        v0 *= WQc;
        v1 *= WQc;
        float c00 = WQc + REGc;
        float c01 = WQc * WQc * (sxi + 64.f * u);
        float c11 = WQc * WQc * sxs2 + REGc;
        float det = c00 * c11 - c01 * c01;
        float inv = 1.0f / det;
        s0s[t] = (c11 * v0 - c01 * v1) * inv;
        s1s[t] = (c00 * v1 - c01 * v0) * inv;
    }
    __syncthreads();

#pragma unroll
    for (int i = 0; i < 8; i++) {
        int e = (i * 256 + t) * 4;
        int nl = e >> 6;
        if (nodeBase + nl < NN) {
            int g = gbase + e;
            int c0 = e & 63;
            float4 fv = *(const float4*)&f[g];
            float4 sv = *(const float4*)&source[g];
            float4 tv = *(const float4*)&trans[g];
            float uu = us[nl];
            float sv0 = s0s[nl], sv1 = s1s[nl];
            float4 ov;
            float* ovp = (float*)&ov;
            const float* fp = (const float*)&fv;
            const float* sp = (const float*)&sv;
            const float* tp = (const float*)&tv;
#pragma unroll
            for (int jj = 0; jj < 4; jj++) {
                float om = bf2f(act[nl * ACT_S + c0 + jj]);
                float xs = xif[c0 + jj] + uu;
                float omst = om - WQc * (sv0 + xs * sv1);
                float val = fmaxf(fp[jj], 0.f) + DTc * (sp[jj] + omst - tp[jj]);
                ovp[jj] = fmaxf(val, 0.f);
            }
            *(float4*)&out[g] = ov;
        }
    }
}

extern "C" void kernel_launch(void* const* d_in, const int* in_sizes, int n_in,
                              void* d_out, int out_size, void* d_ws, size_t ws_size,
                              hipStream_t stream) {
    const float* f       = (const float*)d_in[0];
    const float* macro_u = (const float*)d_in[1];
    const float* source  = (const float*)d_in[2];
    const int*   esrc    = (const int*)d_in[3];
    const int*   edst    = (const int*)d_in[4];
    const float* ew      = (const float*)d_in[5];
    const float* xi      = (const float*)d_in[6];
    const float* w_in    = (const float*)d_in[7];
    const float* b_in    = (const float*)d_in[8];
    const float* w_hid   = (const float*)d_in[9];
    const float* b_hid   = (const float*)d_in[10];
    const float* w_out   = (const float*)d_in[11];
    const float* b_out   = (const float*)d_in[12];
    float* out = (float*)d_out;

    // workspace layout (8-byte entries first)
    u64* adj64 = (u64*)d_ws;                                   // NB*CAP u64 = 29.6 MB (gapped)
    unsigned int* adj4 = (unsigned int*)(adj64 + (size_t)NB * CAP);  // NB*CAP u32 = 14.8 MB (gapped)
    int* deg   = (int*)(adj4 + (size_t)NB * CAP);              // NN (plain stores)
    int* node_offs = deg + NN;                                 // NN (gapped starts)
    int* node_end  = node_offs + NN;                           // NN (gapped ends)
    int* bcur  = node_end + NN;                                // NB used-counts (memset 0)
    float* trans = (float*)(bcur + 784);                       // NN*64
    unsigned short* fb16 = (unsigned short*)(trans + (size_t)NN * 64);  // NN*64 bf16
    unsigned short* wp = fb16 + (size_t)NN * 64;               // 5*4096

    hipMemsetAsync(bcur, 0, 784 * sizeof(int), stream);

    prep_kernel<<<BS_NB + PRE_NB + WP_NB, 256, 0, stream>>>(
        f, (unsigned int*)fb16, w_in, w_hid, w_out, wp, esrc, edst, ew, bcur, adj64);
    bucket_histo<<<NB, 256, 0, stream>>>(bcur, adj64, node_offs, node_end, deg);
    bucket_scatter<<<NB, 256, 0, stream>>>(bcur, adj64, node_offs, deg, adj4);
    gather_kernel<<<(NN + 3) / 4, 256, 0, stream>>>((const unsigned int*)fb16,
                                                    node_offs, node_end, adj4, xi, trans);
    node_kernel<<<(NN + 127) / 128, 256, 0, stream>>>(
        fb16, f, macro_u, source, xi, wp, b_in, b_hid, b_out, trans, out);
}